// Round 3
// baseline (302.282 us; speedup 1.0000x reference)
//
#include <hip/hip_runtime.h>
#include <hip/hip_bf16.h>

// Problem constants (match reference)
constexpr int Bq  = 4;
constexpr int Nn  = 10000;
constexpr int Eq  = 170000;
constexpr int FIN = 256;
constexpr int Ff  = 128;
constexpr int Hh  = 4;
constexpr int M   = Bq * Nn;   // 40000 GEMM rows
constexpr int C   = Hh * Ff;   // 512 GEMM cols
constexpr float LEAKY = 0.2f;

typedef short short8 __attribute__((ext_vector_type(8)));
typedef float f32x4  __attribute__((ext_vector_type(4)));

// float -> bf16 bits, round-to-nearest-even
static __device__ __forceinline__ unsigned short f2bf(float f) {
    unsigned int u = __float_as_uint(f);
    u = u + 0x7fffu + ((u >> 16) & 1u);
    return (unsigned short)(u >> 16);
}
static __device__ __forceinline__ float bf2f(unsigned short b) {
    return __uint_as_float(((unsigned int)b) << 16);
}

// -------------------- K0: Wt[c][k] = bf16(W[h][k][f]), c = h*128+f ------
__global__ void wprep_kernel(const float* __restrict__ W, unsigned short* __restrict__ Wt)
{
    int c = blockIdx.x;   // 0..511
    int k = threadIdx.x;  // 0..255
    float v = W[(size_t)(c >> 7) * FIN * Ff + (size_t)k * Ff + (c & 127)];
    Wt[(size_t)c * FIN + k] = f2bf(v);
}

// -------------------- K1: h = bf16( x @ W + b ), layout (n, b, c) -------
// Block: 32 rows x 512 cols. 4 waves; wave w -> cols [w*128, w*128+128).
// No LDS in K-loop: A-fragments loaded directly from global (block's 32KB
// x-slice fits L1; 4 waves reuse). mfma_f32_16x16x32_bf16 layouts:
//   A-frag: lane l holds A[m=l&15][k=quad*8+j]
//   B-frag: lane l holds B[k=quad*8+j][n=l&15]
//   C/D:    lane l reg r -> row m=quad*4+r, col n=l&15
__global__ __launch_bounds__(256) void gemm_mfma_kernel(
    const float* __restrict__ X, const unsigned short* __restrict__ Wt,
    const float* __restrict__ bias, unsigned short* __restrict__ Hb)
{
    __shared__ unsigned short Ls[32][264]; // epilogue repack (16.9 KB)

    const int row0 = blockIdx.x * 32;
    const int tid  = threadIdx.x;
    const int wave = tid >> 6, lane = tid & 63;
    const int quad = lane >> 4, ln = lane & 15;
    const int n0   = wave * 128;

    f32x4 acc[2][8];
    #pragma unroll
    for (int i = 0; i < 2; ++i)
        #pragma unroll
        for (int j = 0; j < 8; ++j) acc[i][j] = (f32x4){0.f, 0.f, 0.f, 0.f};

    const float* xbase = X + (size_t)(row0 + ln) * FIN;

    #pragma unroll
    for (int ks = 0; ks < 8; ++ks) {
        short8 a[2];
        #pragma unroll
        for (int i = 0; i < 2; ++i) {
            const float* p = xbase + (size_t)i * 16 * FIN + ks * 32 + quad * 8;
            float4 v0 = *(const float4*)p;
            float4 v1 = *(const float4*)(p + 4);
            short8 v;
            v[0] = (short)f2bf(v0.x); v[1] = (short)f2bf(v0.y);
            v[2] = (short)f2bf(v0.z); v[3] = (short)f2bf(v0.w);
            v[4] = (short)f2bf(v1.x); v[5] = (short)f2bf(v1.y);
            v[6] = (short)f2bf(v1.z); v[7] = (short)f2bf(v1.w);
            a[i] = v;
        }
        #pragma unroll
        for (int j = 0; j < 8; ++j) {
            short8 b = *(const short8*)(Wt + (size_t)(n0 + j * 16 + ln) * FIN + ks * 32 + quad * 8);
            acc[0][j] = __builtin_amdgcn_mfma_f32_16x16x32_bf16(a[0], b, acc[0][j], 0, 0, 0);
            acc[1][j] = __builtin_amdgcn_mfma_f32_16x16x32_bf16(a[1], b, acc[1][j], 0, 0, 0);
        }
    }

    // ---- epilogue: +bias, ->bf16, LDS repack, coalesced 16B stores ----
    // output layout: Hb[((n*4)+b)*512 + c]; two passes over col halves.
    #pragma unroll
    for (int r2 = 0; r2 < 2; ++r2) {
        __syncthreads();
        if ((wave >> 1) == r2) {
            int cbase = (wave & 1) * 128;
            #pragma unroll
            for (int j = 0; j < 8; ++j) {
                float bv = bias[n0 + j * 16 + ln];
                #pragma unroll
                for (int i = 0; i < 2; ++i)
                    #pragma unroll
                    for (int r = 0; r < 4; ++r)
                        Ls[i * 16 + quad * 4 + r][cbase + j * 16 + ln] =
                            f2bf(acc[i][j][r] + bv);
            }
        }
        __syncthreads();
        // store 32 rows x 256 shorts = 1024 short8 units; unit u = t + i*256
        #pragma unroll
        for (int i = 0; i < 4; ++i) {
            int u    = tid + i * 256;
            int row  = u >> 5;          // 32 units per row
            int colu = u & 31;
            int mg = row0 + row;
            int bb = mg / Nn;
            int nn = mg - bb * Nn;
            unsigned short* g = Hb + ((size_t)nn * Bq + bb) * C + r2 * 256 + colu * 8;
            *(short8*)g = *(const short8*)&Ls[row][colu * 8];
        }
    }
}

// -------------------- K2: p_src/p_dst from h[-1] (b=3 slice) ------------
// One wave per node; short8 row load; 16-lane xor reduce per head.
__global__ __launch_bounds__(256) void attn_proj_kernel(
    const unsigned short* __restrict__ Hb, const float* __restrict__ Wattn,
    float* __restrict__ p_src, float* __restrict__ p_dst)
{
    int wave = threadIdx.x >> 6, t = threadIdx.x & 63;
    int n = blockIdx.x * 4 + wave;
    if (n >= Nn) return;
    const unsigned short* hrow = Hb + ((size_t)n * Bq + (Bq - 1)) * C;
    short8 hv = *(const short8*)(hrow + t * 8);
    int hi = t >> 4;
    int fb = (t * 8) & 127;
    const float* ws = Wattn + hi * 2 * Ff + fb;
    const float* wd = ws + Ff;
    float4 ws0 = *(const float4*)ws, ws1 = *(const float4*)(ws + 4);
    float4 wd0 = *(const float4*)wd, wd1 = *(const float4*)(wd + 4);
    float h0 = bf2f((unsigned short)hv[0]), h1 = bf2f((unsigned short)hv[1]);
    float h2 = bf2f((unsigned short)hv[2]), h3 = bf2f((unsigned short)hv[3]);
    float h4 = bf2f((unsigned short)hv[4]), h5 = bf2f((unsigned short)hv[5]);
    float h6 = bf2f((unsigned short)hv[6]), h7 = bf2f((unsigned short)hv[7]);
    float as = h0 * ws0.x + h1 * ws0.y + h2 * ws0.z + h3 * ws0.w
             + h4 * ws1.x + h5 * ws1.y + h6 * ws1.z + h7 * ws1.w;
    float ad = h0 * wd0.x + h1 * wd0.y + h2 * wd0.z + h3 * wd0.w
             + h4 * wd1.x + h5 * wd1.y + h6 * wd1.z + h7 * wd1.w;
    #pragma unroll
    for (int off = 1; off < 16; off <<= 1) {
        as += __shfl_xor(as, off, 64);
        ad += __shfl_xor(ad, off, 64);
    }
    if ((t & 15) == 0) { p_src[hi * Nn + n] = as; p_dst[hi * Nn + n] = ad; }
}

// -------------------- K3: row_start via binary search (src sorted) ------
__global__ void row_start_kernel(const int* __restrict__ src, int* __restrict__ row_start)
{
    int n = blockIdx.x * blockDim.x + threadIdx.x;
    if (n > Nn) return;
    int lo = 0, hi = Eq;
    while (lo < hi) { int mid = (lo + hi) >> 1; if (src[mid] < n) lo = mid + 1; else hi = mid; }
    row_start[n] = lo;
}

// -------------------- K4: e = exp(clip(lrelu(s))) -----------------------
__global__ void edge_score_kernel(
    const int* __restrict__ src, const int* __restrict__ dst,
    const float* __restrict__ p_src, const float* __restrict__ p_dst,
    float* __restrict__ eed)
{
    int e = blockIdx.x * blockDim.x + threadIdx.x;
    if (e >= Eq) return;
    int s = src[e], d = dst[e];
    #pragma unroll
    for (int hi = 0; hi < Hh; ++hi) {
        float sc = p_src[hi * Nn + s] + p_dst[hi * Nn + d];
        float lr = sc > 0.f ? sc : LEAKY * sc;
        lr = fminf(fmaxf(lr, -2.f), 2.f);
        eed[(size_t)e * 4 + hi] = __expf(lr);
    }
}

// -------------------- K5: denom -----------------------------------------
__global__ __launch_bounds__(64) void denom_kernel(
    const float4* __restrict__ eed4, const int* __restrict__ row_start,
    float4* __restrict__ denom4)
{
    int n = blockIdx.x;
    int t = threadIdx.x;
    int e0 = row_start[n], e1 = row_start[n + 1];
    float4 acc = {0.f, 0.f, 0.f, 0.f};
    for (int e = e0 + t; e < e1; e += 64) {
        float4 v = eed4[e];
        acc.x += v.x; acc.y += v.y; acc.z += v.z; acc.w += v.w;
    }
    #pragma unroll
    for (int off = 32; off; off >>= 1) {
        acc.x += __shfl_down(acc.x, off, 64);
        acc.y += __shfl_down(acc.y, off, 64);
        acc.z += __shfl_down(acc.z, off, 64);
        acc.w += __shfl_down(acc.w, off, 64);
    }
    if (t == 0) denom4[n] = acc;
}

// -------------------- K6: gather-aggregate (bf16 h, 4-edge unroll) ------
// One block per src node. h row for node d = 2048 bf16 = 4KB contiguous.
// Thread t owns elements [t*8, t*8+8) of (b,hi,f) flat 2048.
__global__ __launch_bounds__(256) void aggregate_kernel(
    const unsigned short* __restrict__ Hb, const float4* __restrict__ eed4,
    const float4* __restrict__ denom4, const int* __restrict__ row_start,
    const int* __restrict__ dst, float* __restrict__ out)
{
    int n = blockIdx.x;
    int t = threadIdx.x;
    int e0 = row_start[n], e1 = row_start[n + 1];
    int hi = (t >> 4) & 3; // head of this thread's 8 elements

    float4 dn = denom4[n];
    float dv  = hi == 0 ? dn.x : hi == 1 ? dn.y : hi == 2 ? dn.z : dn.w;
    float inv = dv != 0.f ? 1.f / dv : 0.f;

    float acc[8];
    #pragma unroll
    for (int k = 0; k < 8; ++k) acc[k] = 0.f;

    int e = e0;
    for (; e + 4 <= e1; e += 4) {
        int d0 = dst[e], d1 = dst[e + 1], d2 = dst[e + 2], d3 = dst[e + 3];
        float4 ev0 = eed4[e], ev1 = eed4[e + 1], ev2 = eed4[e + 2], ev3 = eed4[e + 3];
        short8 v0 = *(const short8*)(Hb + (size_t)d0 * 2048 + t * 8);
        short8 v1 = *(const short8*)(Hb + (size_t)d1 * 2048 + t * 8);
        short8 v2 = *(const short8*)(Hb + (size_t)d2 * 2048 + t * 8);
        short8 v3 = *(const short8*)(Hb + (size_t)d3 * 2048 + t * 8);
        float w0 = (hi == 0 ? ev0.x : hi == 1 ? ev0.y : hi == 2 ? ev0.z : ev0.w) * inv;
        float w1 = (hi == 0 ? ev1.x : hi == 1 ? ev1.y : hi == 2 ? ev1.z : ev1.w) * inv;
        float w2 = (hi == 0 ? ev2.x : hi == 1 ? ev2.y : hi == 2 ? ev2.z : ev2.w) * inv;
        float w3 = (hi == 0 ? ev3.x : hi == 1 ? ev3.y : hi == 2 ? ev3.z : ev3.w) * inv;
        #pragma unroll
        for (int k = 0; k < 8; ++k) acc[k] += bf2f((unsigned short)v0[k]) * w0;
        #pragma unroll
        for (int k = 0; k < 8; ++k) acc[k] += bf2f((unsigned short)v1[k]) * w1;
        #pragma unroll
        for (int k = 0; k < 8; ++k) acc[k] += bf2f((unsigned short)v2[k]) * w2;
        #pragma unroll
        for (int k = 0; k < 8; ++k) acc[k] += bf2f((unsigned short)v3[k]) * w3;
    }
    for (; e < e1; ++e) {
        int d0 = dst[e];
        float4 ev0 = eed4[e];
        float w0 = (hi == 0 ? ev0.x : hi == 1 ? ev0.y : hi == 2 ? ev0.z : ev0.w) * inv;
        short8 v0 = *(const short8*)(Hb + (size_t)d0 * 2048 + t * 8);
        #pragma unroll
        for (int k = 0; k < 8; ++k) acc[k] += bf2f((unsigned short)v0[k]) * w0;
    }

    // out layout (b, n, c): b = t>>6, c = (t&63)*8
    float* g = out + ((size_t)(t >> 6) * Nn + n) * C + (t & 63) * 8;
    float4 o0 = {acc[0], acc[1], acc[2], acc[3]};
    float4 o1 = {acc[4], acc[5], acc[6], acc[7]};
    *(float4*)g       = o0;
    *(float4*)(g + 4) = o1;
}

// -------------------- launch --------------------
extern "C" void kernel_launch(void* const* d_in, const int* in_sizes, int n_in,
                              void* d_out, int out_size, void* d_ws, size_t ws_size,
                              hipStream_t stream)
{
    const float* x      = (const float*)d_in[0]; // (B,N,256)
    const float* W_mlp  = (const float*)d_in[1]; // (H,256,128)
    const float* b_mlp  = (const float*)d_in[2]; // (H,128)
    const float* W_attn = (const float*)d_in[3]; // (H,256,1)
    const int*   src    = (const int*)d_in[4];   // (E,)
    const int*   dst    = (const int*)d_in[5];   // (E,)
    float* out = (float*)d_out;                  // (B,N,512)

    // workspace layout
    unsigned short* h  = (unsigned short*)d_ws;        // M*C bf16 = 40.96 MB
    unsigned short* Wt = h + (size_t)M * C;            // 512*256 bf16
    float* eed   = (float*)(Wt + (size_t)C * FIN);     // E*4 floats
    float* p_src = eed + (size_t)Eq * 4;
    float* p_dst = p_src + (size_t)Hh * Nn;
    float* denom = p_dst + (size_t)Hh * Nn;
    int*   row_st = (int*)(denom + (size_t)Nn * 4);

    hipLaunchKernelGGL(wprep_kernel, dim3(C), dim3(FIN), 0, stream, W_mlp, Wt);

    hipLaunchKernelGGL(gemm_mfma_kernel, dim3(M / 32), dim3(256), 0, stream,
                       x, Wt, b_mlp, h);

    hipLaunchKernelGGL(attn_proj_kernel, dim3((Nn + 3) / 4), dim3(256), 0, stream,
                       h, W_attn, p_src, p_dst);

    hipLaunchKernelGGL(row_start_kernel, dim3((Nn + 256) / 256), dim3(256), 0, stream,
                       src, row_st);

    hipLaunchKernelGGL(edge_score_kernel, dim3((Eq + 255) / 256), dim3(256), 0, stream,
                       src, dst, p_src, p_dst, eed);

    hipLaunchKernelGGL(denom_kernel, dim3(Nn), dim3(64), 0, stream,
                       (const float4*)eed, row_st, (float4*)denom);

    hipLaunchKernelGGL(aggregate_kernel, dim3(Nn), dim3(256), 0, stream,
                       h, (const float4*)eed, (const float4*)denom, row_st, dst, out);
}

// Round 4
// 281.655 us; speedup vs baseline: 1.0732x; 1.0732x over previous
//
#include <hip/hip_runtime.h>
#include <hip/hip_bf16.h>

// Problem constants (match reference)
constexpr int Bq  = 4;
constexpr int Nn  = 10000;
constexpr int Eq  = 170000;
constexpr int FIN = 256;
constexpr int Ff  = 128;
constexpr int Hh  = 4;
constexpr int M   = Bq * Nn;   // 40000 GEMM rows
constexpr int C   = Hh * Ff;   // 512 GEMM cols
constexpr float LEAKY = 0.2f;

typedef short short8 __attribute__((ext_vector_type(8)));
typedef float f32x4  __attribute__((ext_vector_type(4)));

// float -> bf16 bits, round-to-nearest-even
static __device__ __forceinline__ unsigned short f2bf(float f) {
    unsigned int u = __float_as_uint(f);
    u = u + 0x7fffu + ((u >> 16) & 1u);
    return (unsigned short)(u >> 16);
}
static __device__ __forceinline__ float bf2f(unsigned short b) {
    return __uint_as_float(((unsigned int)b) << 16);
}

// -------------------- K-1: xb = bf16(x), same (m,k) layout ---------------
__global__ __launch_bounds__(256) void xprep_kernel(
    const float* __restrict__ X, unsigned short* __restrict__ Xb)
{
    size_t i = ((size_t)blockIdx.x * 256 + threadIdx.x) * 8;
    float4 v0 = *(const float4*)(X + i);
    float4 v1 = *(const float4*)(X + i + 4);
    short8 v;
    v[0] = (short)f2bf(v0.x); v[1] = (short)f2bf(v0.y);
    v[2] = (short)f2bf(v0.z); v[3] = (short)f2bf(v0.w);
    v[4] = (short)f2bf(v1.x); v[5] = (short)f2bf(v1.y);
    v[6] = (short)f2bf(v1.z); v[7] = (short)f2bf(v1.w);
    *(short8*)(Xb + i) = v;
}

// -------------------- K0: Wt in MFMA B-fragment order --------------------
// Fragment unit (16B = 8 shorts): u = ((w*8 + j)*8 + ks)*64 + quad*16 + ln
// holds B[k = ks*32 + quad*8 + el][col = w*128 + j*16 + ln], el = 0..7.
__global__ void wprep_kernel(const float* __restrict__ W, unsigned short* __restrict__ Wtf)
{
    int c = blockIdx.x;   // 0..511 (col = h*128 + f)
    int k = threadIdx.x;  // 0..255
    float v = W[(size_t)(c >> 7) * FIN * Ff + (size_t)k * Ff + (c & 127)];
    int w = c >> 7, j = (c >> 4) & 7, ln = c & 15;
    int ks = k >> 5, quad = (k >> 3) & 3, el = k & 7;
    size_t u = ((size_t)((w * 8 + j) * 8 + ks) * 4 + quad) * 16 + ln;
    Wtf[u * 8 + el] = f2bf(v);
}

// -------------------- K1: h = bf16( xb @ W + b ), layout (n, b, c) -------
// Block: 32 rows x 512 cols. Wave w -> cols [w*128, w*128+128).
// K-loop: 2 ds_read_b128 (A) + 8 coalesced global dwordx4 (B) + 16 MFMA per ks.
__global__ __launch_bounds__(256) void gemm_mfma_kernel(
    const unsigned short* __restrict__ Xb, const unsigned short* __restrict__ Wtf,
    const float* __restrict__ bias, unsigned short* __restrict__ Hb)
{
    __shared__ unsigned short As[32][264]; // 16.9 KB; reused for epilogue repack

    const int row0 = blockIdx.x * 32;
    const int tid  = threadIdx.x;
    const int wave = tid >> 6, lane = tid & 63;
    const int quad = lane >> 4, ln = lane & 15;
    const int n0   = wave * 128;

    // stage A tile (32 rows x 256 k bf16 = 16 KB), fully coalesced
    #pragma unroll
    for (int i = 0; i < 4; ++i) {
        int u = tid + i * 256;           // 1024 units of 8 shorts
        int row = u >> 5, cu = u & 31;
        *(short8*)&As[row][cu * 8] =
            *(const short8*)(Xb + (size_t)(row0 + row) * FIN + cu * 8);
    }
    __syncthreads();

    f32x4 acc[2][8];
    #pragma unroll
    for (int i = 0; i < 2; ++i)
        #pragma unroll
        for (int j = 0; j < 8; ++j) acc[i][j] = (f32x4){0.f, 0.f, 0.f, 0.f};

    const short8* Wf8 = (const short8*)Wtf;

    #pragma unroll
    for (int ks = 0; ks < 8; ++ks) {
        short8 a0 = *(const short8*)&As[ln][ks * 32 + quad * 8];
        short8 a1 = *(const short8*)&As[16 + ln][ks * 32 + quad * 8];
        #pragma unroll
        for (int j = 0; j < 8; ++j) {
            short8 b = Wf8[(size_t)((wave * 8 + j) * 8 + ks) * 64 + lane];
            acc[0][j] = __builtin_amdgcn_mfma_f32_16x16x32_bf16(a0, b, acc[0][j], 0, 0, 0);
            acc[1][j] = __builtin_amdgcn_mfma_f32_16x16x32_bf16(a1, b, acc[1][j], 0, 0, 0);
        }
    }

    // ---- epilogue: +bias, ->bf16, LDS repack, coalesced 16B stores ----
    // output layout: Hb[((n*4)+b)*512 + c]; two passes over 256-col halves.
    #pragma unroll
    for (int r2 = 0; r2 < 2; ++r2) {
        __syncthreads();
        if ((wave >> 1) == r2) {
            int cbase = (wave & 1) * 128;
            #pragma unroll
            for (int j = 0; j < 8; ++j) {
                float bv = bias[n0 + j * 16 + ln];
                #pragma unroll
                for (int i = 0; i < 2; ++i)
                    #pragma unroll
                    for (int r = 0; r < 4; ++r)
                        As[i * 16 + quad * 4 + r][cbase + j * 16 + ln] =
                            f2bf(acc[i][j][r] + bv);
            }
        }
        __syncthreads();
        #pragma unroll
        for (int i = 0; i < 4; ++i) {
            int u    = tid + i * 256;
            int row  = u >> 5;
            int colu = u & 31;
            int mg = row0 + row;
            int bb = mg / Nn;
            int nn = mg - bb * Nn;
            unsigned short* g = Hb + ((size_t)nn * Bq + bb) * C + r2 * 256 + colu * 8;
            *(short8*)g = *(const short8*)&As[row][colu * 8];
        }
    }
}

// -------------------- K2: p_src/p_dst from h[-1] (b=3 slice) ------------
__global__ __launch_bounds__(256) void attn_proj_kernel(
    const unsigned short* __restrict__ Hb, const float* __restrict__ Wattn,
    float* __restrict__ p_src, float* __restrict__ p_dst)
{
    int wave = threadIdx.x >> 6, t = threadIdx.x & 63;
    int n = blockIdx.x * 4 + wave;
    if (n >= Nn) return;
    const unsigned short* hrow = Hb + ((size_t)n * Bq + (Bq - 1)) * C;
    short8 hv = *(const short8*)(hrow + t * 8);
    int hi = t >> 4;
    int fb = (t * 8) & 127;
    const float* ws = Wattn + hi * 2 * Ff + fb;
    const float* wd = ws + Ff;
    float4 ws0 = *(const float4*)ws, ws1 = *(const float4*)(ws + 4);
    float4 wd0 = *(const float4*)wd, wd1 = *(const float4*)(wd + 4);
    float h0 = bf2f((unsigned short)hv[0]), h1 = bf2f((unsigned short)hv[1]);
    float h2 = bf2f((unsigned short)hv[2]), h3 = bf2f((unsigned short)hv[3]);
    float h4 = bf2f((unsigned short)hv[4]), h5 = bf2f((unsigned short)hv[5]);
    float h6 = bf2f((unsigned short)hv[6]), h7 = bf2f((unsigned short)hv[7]);
    float as = h0 * ws0.x + h1 * ws0.y + h2 * ws0.z + h3 * ws0.w
             + h4 * ws1.x + h5 * ws1.y + h6 * ws1.z + h7 * ws1.w;
    float ad = h0 * wd0.x + h1 * wd0.y + h2 * wd0.z + h3 * wd0.w
             + h4 * wd1.x + h5 * wd1.y + h6 * wd1.z + h7 * wd1.w;
    #pragma unroll
    for (int off = 1; off < 16; off <<= 1) {
        as += __shfl_xor(as, off, 64);
        ad += __shfl_xor(ad, off, 64);
    }
    if ((t & 15) == 0) { p_src[hi * Nn + n] = as; p_dst[hi * Nn + n] = ad; }
}

// -------------------- K3: row_start via binary search (src sorted) ------
__global__ void row_start_kernel(const int* __restrict__ src, int* __restrict__ row_start)
{
    int n = blockIdx.x * blockDim.x + threadIdx.x;
    if (n > Nn) return;
    int lo = 0, hi = Eq;
    while (lo < hi) { int mid = (lo + hi) >> 1; if (src[mid] < n) lo = mid + 1; else hi = mid; }
    row_start[n] = lo;
}

// -------------------- K4: e = exp(clip(lrelu(s))) -----------------------
__global__ void edge_score_kernel(
    const int* __restrict__ src, const int* __restrict__ dst,
    const float* __restrict__ p_src, const float* __restrict__ p_dst,
    float* __restrict__ eed)
{
    int e = blockIdx.x * blockDim.x + threadIdx.x;
    if (e >= Eq) return;
    int s = src[e], d = dst[e];
    #pragma unroll
    for (int hi = 0; hi < Hh; ++hi) {
        float sc = p_src[hi * Nn + s] + p_dst[hi * Nn + d];
        float lr = sc > 0.f ? sc : LEAKY * sc;
        lr = fminf(fmaxf(lr, -2.f), 2.f);
        eed[(size_t)e * 4 + hi] = __expf(lr);
    }
}

// -------------------- K5: denom -----------------------------------------
__global__ __launch_bounds__(64) void denom_kernel(
    const float4* __restrict__ eed4, const int* __restrict__ row_start,
    float4* __restrict__ denom4)
{
    int n = blockIdx.x;
    int t = threadIdx.x;
    int e0 = row_start[n], e1 = row_start[n + 1];
    float4 acc = {0.f, 0.f, 0.f, 0.f};
    for (int e = e0 + t; e < e1; e += 64) {
        float4 v = eed4[e];
        acc.x += v.x; acc.y += v.y; acc.z += v.z; acc.w += v.w;
    }
    #pragma unroll
    for (int off = 32; off; off >>= 1) {
        acc.x += __shfl_down(acc.x, off, 64);
        acc.y += __shfl_down(acc.y, off, 64);
        acc.z += __shfl_down(acc.z, off, 64);
        acc.w += __shfl_down(acc.w, off, 64);
    }
    if (t == 0) denom4[n] = acc;
}

// -------------------- K6: gather-aggregate, edge-per-wave ----------------
// One block per src node. Wave w processes edges e0+w, e0+w+4, ... and
// accumulates the FULL 2048-elem row (acc[4][8] per lane, 4x 1KB coalesced
// loads per edge, 2-edge unroll -> 8 loads in flight). Cross-wave LDS reduce.
__global__ __launch_bounds__(256) void aggregate_kernel(
    const unsigned short* __restrict__ Hb, const float4* __restrict__ eed4,
    const float4* __restrict__ denom4, const int* __restrict__ row_start,
    const int* __restrict__ dst, float* __restrict__ out)
{
    __shared__ float Ls[4][2048]; // 32 KB

    int n = blockIdx.x;
    int tid = threadIdx.x;
    int wave = tid >> 6, t = tid & 63;
    int e0 = row_start[n], e1 = row_start[n + 1];
    int hi = (t >> 4) & 3; // head of this lane's 8-elem chunk (same for all 4 segments)

    float4 dn = denom4[n];
    float dv  = hi == 0 ? dn.x : hi == 1 ? dn.y : hi == 2 ? dn.z : dn.w;
    float inv = dv != 0.f ? 1.f / dv : 0.f;

    float acc[4][8];
    #pragma unroll
    for (int s = 0; s < 4; ++s)
        #pragma unroll
        for (int k = 0; k < 8; ++k) acc[s][k] = 0.f;

    int e = e0 + wave;
    for (; e + 4 < e1; e += 8) {
        int d0 = dst[e], d1 = dst[e + 4];
        float4 ev0 = eed4[e], ev1 = eed4[e + 4];
        float w0 = (hi == 0 ? ev0.x : hi == 1 ? ev0.y : hi == 2 ? ev0.z : ev0.w) * inv;
        float w1 = (hi == 0 ? ev1.x : hi == 1 ? ev1.y : hi == 2 ? ev1.z : ev1.w) * inv;
        const short8* hp0 = (const short8*)(Hb + (size_t)d0 * 2048) + t;
        const short8* hp1 = (const short8*)(Hb + (size_t)d1 * 2048) + t;
        short8 v00 = hp0[0], v01 = hp0[64], v02 = hp0[128], v03 = hp0[192];
        short8 v10 = hp1[0], v11 = hp1[64], v12 = hp1[128], v13 = hp1[192];
        #pragma unroll
        for (int k = 0; k < 8; ++k) {
            acc[0][k] += bf2f((unsigned short)v00[k]) * w0;
            acc[1][k] += bf2f((unsigned short)v01[k]) * w0;
            acc[2][k] += bf2f((unsigned short)v02[k]) * w0;
            acc[3][k] += bf2f((unsigned short)v03[k]) * w0;
        }
        #pragma unroll
        for (int k = 0; k < 8; ++k) {
            acc[0][k] += bf2f((unsigned short)v10[k]) * w1;
            acc[1][k] += bf2f((unsigned short)v11[k]) * w1;
            acc[2][k] += bf2f((unsigned short)v12[k]) * w1;
            acc[3][k] += bf2f((unsigned short)v13[k]) * w1;
        }
    }
    if (e < e1) {
        int d0 = dst[e];
        float4 ev0 = eed4[e];
        float w0 = (hi == 0 ? ev0.x : hi == 1 ? ev0.y : hi == 2 ? ev0.z : ev0.w) * inv;
        const short8* hp0 = (const short8*)(Hb + (size_t)d0 * 2048) + t;
        short8 v00 = hp0[0], v01 = hp0[64], v02 = hp0[128], v03 = hp0[192];
        #pragma unroll
        for (int k = 0; k < 8; ++k) {
            acc[0][k] += bf2f((unsigned short)v00[k]) * w0;
            acc[1][k] += bf2f((unsigned short)v01[k]) * w0;
            acc[2][k] += bf2f((unsigned short)v02[k]) * w0;
            acc[3][k] += bf2f((unsigned short)v03[k]) * w0;
        }
    }

    // write partials, cross-wave reduce
    #pragma unroll
    for (int s = 0; s < 4; ++s) {
        float4 p0 = {acc[s][0], acc[s][1], acc[s][2], acc[s][3]};
        float4 p1 = {acc[s][4], acc[s][5], acc[s][6], acc[s][7]};
        *(float4*)&Ls[wave][s * 512 + t * 8]     = p0;
        *(float4*)&Ls[wave][s * 512 + t * 8 + 4] = p1;
    }
    __syncthreads();

    // thread tid owns output elems [tid*8, tid*8+8); b = tid>>6, c = (tid&63)*8
    float4 r0 = {0.f, 0.f, 0.f, 0.f}, r1 = {0.f, 0.f, 0.f, 0.f};
    #pragma unroll
    for (int w = 0; w < 4; ++w) {
        float4 a0 = *(const float4*)&Ls[w][tid * 8];
        float4 a1 = *(const float4*)&Ls[w][tid * 8 + 4];
        r0.x += a0.x; r0.y += a0.y; r0.z += a0.z; r0.w += a0.w;
        r1.x += a1.x; r1.y += a1.y; r1.z += a1.z; r1.w += a1.w;
    }
    float* g = out + ((size_t)(tid >> 6) * Nn + n) * C + (tid & 63) * 8;
    *(float4*)g       = r0;
    *(float4*)(g + 4) = r1;
}

// -------------------- launch --------------------
extern "C" void kernel_launch(void* const* d_in, const int* in_sizes, int n_in,
                              void* d_out, int out_size, void* d_ws, size_t ws_size,
                              hipStream_t stream)
{
    const float* x      = (const float*)d_in[0]; // (B,N,256)
    const float* W_mlp  = (const float*)d_in[1]; // (H,256,128)
    const float* b_mlp  = (const float*)d_in[2]; // (H,128)
    const float* W_attn = (const float*)d_in[3]; // (H,256,1)
    const int*   src    = (const int*)d_in[4];   // (E,)
    const int*   dst    = (const int*)d_in[5];   // (E,)
    float* out = (float*)d_out;                  // (B,N,512)

    // workspace layout
    unsigned short* h   = (unsigned short*)d_ws;       // M*C bf16 = 40.96 MB
    unsigned short* Wtf = h + (size_t)M * C;           // 512*256 bf16 (fragment order)
    unsigned short* xb  = Wtf + (size_t)C * FIN;       // M*FIN bf16 = 20.48 MB
    float* eed   = (float*)(xb + (size_t)M * FIN);     // E*4 floats
    float* p_src = eed + (size_t)Eq * 4;
    float* p_dst = p_src + (size_t)Hh * Nn;
    float* denom = p_dst + (size_t)Hh * Nn;
    int*   row_st = (int*)(denom + (size_t)Nn * 4);

    hipLaunchKernelGGL(xprep_kernel, dim3((M * FIN) / (256 * 8)), dim3(256), 0, stream, x, xb);
    hipLaunchKernelGGL(wprep_kernel, dim3(C), dim3(FIN), 0, stream, W_mlp, Wtf);

    hipLaunchKernelGGL(gemm_mfma_kernel, dim3(M / 32), dim3(256), 0, stream,
                       xb, Wtf, b_mlp, h);

    hipLaunchKernelGGL(attn_proj_kernel, dim3((Nn + 3) / 4), dim3(256), 0, stream,
                       h, W_attn, p_src, p_dst);

    hipLaunchKernelGGL(row_start_kernel, dim3((Nn + 256) / 256), dim3(256), 0, stream,
                       src, row_st);

    hipLaunchKernelGGL(edge_score_kernel, dim3((Eq + 255) / 256), dim3(256), 0, stream,
                       src, dst, p_src, p_dst, eed);

    hipLaunchKernelGGL(denom_kernel, dim3(Nn), dim3(64), 0, stream,
                       (const float4*)eed, row_st, (float4*)denom);

    hipLaunchKernelGGL(aggregate_kernel, dim3(Nn), dim3(256), 0, stream,
                       h, (const float4*)eed, (const float4*)denom, row_st, dst, out);
}

// Round 5
// 239.320 us; speedup vs baseline: 1.2631x; 1.1769x over previous
//
#include <hip/hip_runtime.h>
#include <hip/hip_bf16.h>

// Problem constants (match reference)
constexpr int Bq  = 4;
constexpr int Nn  = 10000;
constexpr int Eq  = 170000;
constexpr int FIN = 256;
constexpr int Ff  = 128;
constexpr int Hh  = 4;
constexpr int Mrows = Nn * Bq;  // per-head GEMM2 M = 40000 (n*4+b)
constexpr int C   = Hh * Ff;    // 512 output cols
constexpr float LEAKY = 0.2f;

typedef short short4v __attribute__((ext_vector_type(4)));
typedef short short8  __attribute__((ext_vector_type(8)));
typedef float f32x4   __attribute__((ext_vector_type(4)));

// float -> bf16 bits, round-to-nearest-even
static __device__ __forceinline__ unsigned short f2bf(float f) {
    unsigned int u = __float_as_uint(f);
    u = u + 0x7fffu + ((u >> 16) & 1u);
    return (unsigned short)(u >> 16);
}
static __device__ __forceinline__ float bf2f(unsigned short b) {
    return __uint_as_float(((unsigned int)b) << 16);
}

// ---------- K1: Xb[n][b][k] = bf16(x[b][n][k]) — gather-friendly layout ----
__global__ __launch_bounds__(256) void xprep2_kernel(
    const float* __restrict__ X, unsigned short* __restrict__ Xb)
{
    int n0 = blockIdx.x * 8;
    int t  = threadIdx.x;
    int r  = t >> 5;          // 0..7
    int k8 = (t & 31) * 8;    // 0..248
    #pragma unroll
    for (int b = 0; b < Bq; ++b) {
        const float* p = X + ((size_t)b * Nn + n0 + r) * FIN + k8;
        float4 v0 = *(const float4*)p, v1 = *(const float4*)(p + 4);
        short8 v;
        v[0] = (short)f2bf(v0.x); v[1] = (short)f2bf(v0.y);
        v[2] = (short)f2bf(v0.z); v[3] = (short)f2bf(v0.w);
        v[4] = (short)f2bf(v1.x); v[5] = (short)f2bf(v1.y);
        v[6] = (short)f2bf(v1.z); v[7] = (short)f2bf(v1.w);
        *(short8*)(Xb + ((size_t)(n0 + r) * Bq + b) * FIN + k8) = v;
    }
}

// ---------- K2: Wf in MFMA B-fragment order (same as r4) -------------------
// unit u = ((hi*8 + j)*8 + ks)*64 + quad*16 + ln holds
// B[k = ks*32 + quad*8 + el][col = hi*128 + j*16 + ln], el = 0..7.
__global__ void wprep_kernel(const float* __restrict__ W, unsigned short* __restrict__ Wf)
{
    int c = blockIdx.x;   // 0..511 (col = hi*128 + f)
    int k = threadIdx.x;  // 0..255
    float v = W[(size_t)(c >> 7) * FIN * Ff + (size_t)k * Ff + (c & 127)];
    int w = c >> 7, j = (c >> 4) & 7, ln = c & 15;
    int ks = k >> 5, quad = (k >> 3) & 3, el = k & 7;
    size_t u = ((size_t)((w * 8 + j) * 8 + ks) * 4 + quad) * 16 + ln;
    Wf[u * 8 + el] = f2bf(v);
}

// ---------- K3: wa[v][hi][k] = sum_f W[hi][k][f]*a_v[hi][f]; bsd[v][hi] ----
__global__ __launch_bounds__(256) void waprep_kernel(
    const float* __restrict__ W, const float* __restrict__ Wattn,
    const float* __restrict__ bmlp, float* __restrict__ wa, float* __restrict__ bsd)
{
    int t = threadIdx.x;
    int hi = t >> 6, kb = t & 63;
    #pragma unroll
    for (int i = 0; i < 4; ++i) {
        int k = kb + i * 64;
        float ss = 0.f, sd = 0.f;
        const float* wrow = W + ((size_t)hi * FIN + k) * Ff;
        const float* as = Wattn + hi * 2 * Ff;
        const float* ad = as + Ff;
        for (int f = 0; f < Ff; f += 4) {
            float4 wv = *(const float4*)(wrow + f);
            float4 av = *(const float4*)(as + f);
            float4 dv = *(const float4*)(ad + f);
            ss += wv.x * av.x + wv.y * av.y + wv.z * av.z + wv.w * av.w;
            sd += wv.x * dv.x + wv.y * dv.y + wv.z * dv.z + wv.w * dv.w;
        }
        wa[(0 * 4 + hi) * FIN + k] = ss;
        wa[(1 * 4 + hi) * FIN + k] = sd;
    }
    if (t < 8) {
        int v = t & 1, hh = t >> 1;
        float s = 0.f;
        for (int f = 0; f < Ff; ++f)
            s += bmlp[hh * Ff + f] * Wattn[hh * 2 * Ff + v * Ff + f];
        bsd[v * 4 + hh] = s;
    }
}

// ---------- K4: psT[n][hi], pdT[n][hi] from fp32 x[3] ----------------------
__global__ __launch_bounds__(256) void pproj_kernel(
    const float* __restrict__ X, const float* __restrict__ wa,
    const float* __restrict__ bsd, float* __restrict__ psT, float* __restrict__ pdT)
{
    int wave = threadIdx.x >> 6, l = threadIdx.x & 63;
    int n = blockIdx.x * 4 + wave;
    if (n >= Nn) return;
    float4 xv = *(const float4*)(X + ((size_t)(Bq - 1) * Nn + n) * FIN + l * 4);
    float s[8];
    #pragma unroll
    for (int i = 0; i < 8; ++i) {
        float4 wv = *(const float4*)(wa + (size_t)i * FIN + l * 4);
        s[i] = xv.x * wv.x + xv.y * wv.y + xv.z * wv.z + xv.w * wv.w;
    }
    #pragma unroll
    for (int off = 1; off < 64; off <<= 1)
        #pragma unroll
        for (int i = 0; i < 8; ++i) s[i] += __shfl_xor(s[i], off, 64);
    if (l == 0) {
        #pragma unroll
        for (int hi = 0; hi < 4; ++hi) {
            psT[n * 4 + hi] = s[hi]     + bsd[hi];
            pdT[n * 4 + hi] = s[4 + hi] + bsd[4 + hi];
        }
    }
}

// ---------- K5: row_start via binary search (src sorted) -------------------
__global__ void row_start_kernel(const int* __restrict__ src, int* __restrict__ row_start)
{
    int n = blockIdx.x * blockDim.x + threadIdx.x;
    if (n > Nn) return;
    int lo = 0, hi = Eq;
    while (lo < hi) { int mid = (lo + hi) >> 1; if (src[mid] < n) lo = mid + 1; else hi = mid; }
    row_start[n] = lo;
}

// ---------- K6: fused edge scores + denom (block per node) -----------------
__global__ __launch_bounds__(64) void edge_denom_kernel(
    const int* __restrict__ dst, const int* __restrict__ row_start,
    const float* __restrict__ psT, const float* __restrict__ pdT,
    float* __restrict__ eed, float* __restrict__ denom)
{
    int n = blockIdx.x, t = threadIdx.x;
    int e0 = row_start[n], e1 = row_start[n + 1];
    float4 ps = *(const float4*)(psT + (size_t)n * 4);
    float4 acc = {0.f, 0.f, 0.f, 0.f};
    for (int e = e0 + t; e < e1; e += 64) {
        int d = dst[e];
        float4 pd = *(const float4*)(pdT + (size_t)d * 4);
        float4 ev;
        {
            float sc = ps.x + pd.x; float lr = sc > 0.f ? sc : LEAKY * sc;
            ev.x = __expf(fminf(fmaxf(lr, -2.f), 2.f));
        }
        {
            float sc = ps.y + pd.y; float lr = sc > 0.f ? sc : LEAKY * sc;
            ev.y = __expf(fminf(fmaxf(lr, -2.f), 2.f));
        }
        {
            float sc = ps.z + pd.z; float lr = sc > 0.f ? sc : LEAKY * sc;
            ev.z = __expf(fminf(fmaxf(lr, -2.f), 2.f));
        }
        {
            float sc = ps.w + pd.w; float lr = sc > 0.f ? sc : LEAKY * sc;
            ev.w = __expf(fminf(fmaxf(lr, -2.f), 2.f));
        }
        *(float4*)(eed + (size_t)e * 4) = ev;
        acc.x += ev.x; acc.y += ev.y; acc.z += ev.z; acc.w += ev.w;
    }
    #pragma unroll
    for (int off = 32; off; off >>= 1) {
        acc.x += __shfl_down(acc.x, off, 64);
        acc.y += __shfl_down(acc.y, off, 64);
        acc.z += __shfl_down(acc.z, off, 64);
        acc.w += __shfl_down(acc.w, off, 64);
    }
    if (t == 0) *(float4*)(denom + (size_t)n * 4) = acc;
}

// ---------- K7: gather gx[hi][n*4+b][k] = sum_e w[hi,e]*x[b,dst_e,k] -------
// Block per node; per edge one 2KB coalesced read (Xb row). Thread t:
// b = t>>6, k0 = (t&63)*4; acc[hi][0..3]. 4-edge unroll.
__global__ __launch_bounds__(256) void gather_kernel(
    const unsigned short* __restrict__ Xb, const float* __restrict__ eed,
    const float* __restrict__ denom, const int* __restrict__ row_start,
    const int* __restrict__ dst, unsigned short* __restrict__ Gx)
{
    int n = blockIdx.x, t = threadIdx.x;
    int e0 = row_start[n], e1 = row_start[n + 1];
    float4 dn = *(const float4*)(denom + (size_t)n * 4);
    float inv0 = dn.x != 0.f ? 1.f / dn.x : 0.f;
    float inv1 = dn.y != 0.f ? 1.f / dn.y : 0.f;
    float inv2 = dn.z != 0.f ? 1.f / dn.z : 0.f;
    float inv3 = dn.w != 0.f ? 1.f / dn.w : 0.f;

    float acc[4][4];
    #pragma unroll
    for (int hi = 0; hi < 4; ++hi)
        #pragma unroll
        for (int j = 0; j < 4; ++j) acc[hi][j] = 0.f;

    const float4* eed4 = (const float4*)eed;
    int off = t * 4;

    int e = e0;
    for (; e + 4 <= e1; e += 4) {
        int d0 = dst[e], d1 = dst[e + 1], d2 = dst[e + 2], d3 = dst[e + 3];
        short4v v0 = *(const short4v*)(Xb + (size_t)d0 * 1024 + off);
        short4v v1 = *(const short4v*)(Xb + (size_t)d1 * 1024 + off);
        short4v v2 = *(const short4v*)(Xb + (size_t)d2 * 1024 + off);
        short4v v3 = *(const short4v*)(Xb + (size_t)d3 * 1024 + off);
        float4 ev0 = eed4[e], ev1 = eed4[e + 1], ev2 = eed4[e + 2], ev3 = eed4[e + 3];
        float w[4][4] = {
            {ev0.x * inv0, ev0.y * inv1, ev0.z * inv2, ev0.w * inv3},
            {ev1.x * inv0, ev1.y * inv1, ev1.z * inv2, ev1.w * inv3},
            {ev2.x * inv0, ev2.y * inv1, ev2.z * inv2, ev2.w * inv3},
            {ev3.x * inv0, ev3.y * inv1, ev3.z * inv2, ev3.w * inv3}};
        #pragma unroll
        for (int j = 0; j < 4; ++j) {
            float f0 = bf2f((unsigned short)v0[j]);
            float f1 = bf2f((unsigned short)v1[j]);
            float f2 = bf2f((unsigned short)v2[j]);
            float f3 = bf2f((unsigned short)v3[j]);
            #pragma unroll
            for (int hi = 0; hi < 4; ++hi)
                acc[hi][j] += f0 * w[0][hi] + f1 * w[1][hi] + f2 * w[2][hi] + f3 * w[3][hi];
        }
    }
    for (; e < e1; ++e) {
        int d0 = dst[e];
        short4v v0 = *(const short4v*)(Xb + (size_t)d0 * 1024 + off);
        float4 ev0 = eed4[e];
        float w0 = ev0.x * inv0, w1 = ev0.y * inv1, w2 = ev0.z * inv2, w3 = ev0.w * inv3;
        #pragma unroll
        for (int j = 0; j < 4; ++j) {
            float f = bf2f((unsigned short)v0[j]);
            acc[0][j] += f * w0; acc[1][j] += f * w1;
            acc[2][j] += f * w2; acc[3][j] += f * w3;
        }
    }

    int b = t >> 6, k0 = (t & 63) * 4;
    #pragma unroll
    for (int hi = 0; hi < 4; ++hi) {
        short4v o;
        #pragma unroll
        for (int j = 0; j < 4; ++j) o[j] = (short)f2bf(acc[hi][j]);
        *(short4v*)(Gx + ((size_t)hi * Mrows + (size_t)n * 4 + b) * FIN + k0) = o;
    }
}

// ---------- K8: out = Gx @ W[hi] + bias*(denom!=0), per head ---------------
// Block: head hi (blockIdx.y), 32 M-rows (n*4+b) x 128 cols. 4 waves, wave w
// handles j in {2w, 2w+1}; K=256 in 8 ks steps.
__global__ __launch_bounds__(256) void gemm2_kernel(
    const unsigned short* __restrict__ Gx, const unsigned short* __restrict__ Wf,
    const float* __restrict__ bias, const float* __restrict__ denom,
    float* __restrict__ out)
{
    __shared__ unsigned short As[32][264];

    const int hi = blockIdx.y;
    const int r0 = blockIdx.x * 32;
    const int tid = threadIdx.x;
    const int wave = tid >> 6, lane = tid & 63;
    const int quad = lane >> 4, ln = lane & 15;

    const unsigned short* Arows = Gx + ((size_t)hi * Mrows + r0) * FIN;
    #pragma unroll
    for (int i = 0; i < 4; ++i) {
        int u = tid + i * 256;
        int row = u >> 5, cu = u & 31;
        *(short8*)&As[row][cu * 8] = *(const short8*)(Arows + (size_t)row * FIN + cu * 8);
    }
    __syncthreads();

    f32x4 acc[2][2];
    #pragma unroll
    for (int i = 0; i < 2; ++i)
        #pragma unroll
        for (int j = 0; j < 2; ++j) acc[i][j] = (f32x4){0.f, 0.f, 0.f, 0.f};

    const short8* Wf8 = (const short8*)Wf;
    #pragma unroll
    for (int ks = 0; ks < 8; ++ks) {
        short8 a0 = *(const short8*)&As[ln][ks * 32 + quad * 8];
        short8 a1 = *(const short8*)&As[16 + ln][ks * 32 + quad * 8];
        #pragma unroll
        for (int jj = 0; jj < 2; ++jj) {
            int j = wave * 2 + jj;
            short8 b = Wf8[(size_t)((hi * 8 + j) * 8 + ks) * 64 + lane];
            acc[0][jj] = __builtin_amdgcn_mfma_f32_16x16x32_bf16(a0, b, acc[0][jj], 0, 0, 0);
            acc[1][jj] = __builtin_amdgcn_mfma_f32_16x16x32_bf16(a1, b, acc[1][jj], 0, 0, 0);
        }
    }

    // epilogue: direct stores; bias guarded by denom!=0 (empty segments)
    #pragma unroll
    for (int jj = 0; jj < 2; ++jj) {
        int colf = (wave * 2 + jj) * 16 + ln;   // col within head, 0..127
        float bv = bias[hi * Ff + colf];
        #pragma unroll
        for (int mt = 0; mt < 2; ++mt) {
            #pragma unroll
            for (int r = 0; r < 4; ++r) {
                int m = mt * 16 + quad * 4 + r;
                int g = r0 + m;
                int nn = g >> 2, bb = g & 3;
                float flag = denom[(size_t)nn * 4 + hi] != 0.f ? 1.f : 0.f;
                out[((size_t)bb * Nn + nn) * C + hi * Ff + colf] = acc[mt][jj][r] + bv * flag;
            }
        }
    }
}

// -------------------- launch --------------------
extern "C" void kernel_launch(void* const* d_in, const int* in_sizes, int n_in,
                              void* d_out, int out_size, void* d_ws, size_t ws_size,
                              hipStream_t stream)
{
    const float* x      = (const float*)d_in[0]; // (B,N,256)
    const float* W_mlp  = (const float*)d_in[1]; // (H,256,128)
    const float* b_mlp  = (const float*)d_in[2]; // (H,128)
    const float* W_attn = (const float*)d_in[3]; // (H,256,1)
    const int*   src    = (const int*)d_in[4];   // (E,)
    const int*   dst    = (const int*)d_in[5];   // (E,)
    float* out = (float*)d_out;                  // (B,N,512)

    // workspace layout (16B-aligned chunks)
    unsigned short* Gx  = (unsigned short*)d_ws;          // 4*40000*256 bf16 = 81.92 MB
    unsigned short* Xb  = Gx + (size_t)Hh * Mrows * FIN;  // 10000*4*256 bf16 = 20.48 MB
    unsigned short* Wf  = Xb + (size_t)Nn * Bq * FIN;     // 512*256 bf16
    float* eed   = (float*)(Wf + (size_t)C * FIN);        // E*4 floats
    float* psT   = eed + (size_t)Eq * 4;                  // N*4
    float* pdT   = psT + (size_t)Nn * 4;                  // N*4
    float* denom = pdT + (size_t)Nn * 4;                  // N*4
    float* wa    = denom + (size_t)Nn * 4;                // 2*4*256
    float* bsd   = wa + 2 * 4 * FIN;                      // 8 (pad 16)
    int*   row_st = (int*)(bsd + 16);                     // N+1

    hipLaunchKernelGGL(xprep2_kernel, dim3(Nn / 8), dim3(256), 0, stream, x, Xb);
    hipLaunchKernelGGL(wprep_kernel, dim3(C), dim3(FIN), 0, stream, W_mlp, Wf);
    hipLaunchKernelGGL(waprep_kernel, dim3(1), dim3(256), 0, stream,
                       W_mlp, W_attn, b_mlp, wa, bsd);
    hipLaunchKernelGGL(pproj_kernel, dim3(Nn / 4), dim3(256), 0, stream,
                       x, wa, bsd, psT, pdT);
    hipLaunchKernelGGL(row_start_kernel, dim3((Nn + 256) / 256), dim3(256), 0, stream,
                       src, row_st);
    hipLaunchKernelGGL(edge_denom_kernel, dim3(Nn), dim3(64), 0, stream,
                       dst, row_st, psT, pdT, eed, denom);
    hipLaunchKernelGGL(gather_kernel, dim3(Nn), dim3(256), 0, stream,
                       Xb, eed, denom, row_st, dst, Gx);
    hipLaunchKernelGGL(gemm2_kernel, dim3(Mrows / 32, Hh), dim3(256), 0, stream,
                       Gx, Wf, b_mlp, denom, out);
}